// Round 18
// baseline (50.960 us; speedup 1.0000x reference)
//
#include <hip/hip_runtime.h>
#include <hip/hip_fp16.h>

#define NPTS    8192
#define NB      4
#define TOTPTS  32768
#define VSTRB   288   // BYTES per point in V: [u(16B) | v(16+kk*16+m, 256B) | pad(16B)]
// Yg layout per point (128 fp8 bytes): byte 2c = y3[c], 2c+1 = y3[c+64]

typedef __attribute__((ext_vector_type(8))) short bf16x8;
typedef __attribute__((ext_vector_type(4))) float f32x4;
typedef __attribute__((ext_vector_type(2))) float vf2;
typedef _Float16 half2_t __attribute__((ext_vector_type(2)));

static __device__ __forceinline__ ushort f2bf(float f) {
  unsigned u = __float_as_uint(f);
  unsigned r = (u + 0x7FFFu + ((u >> 16) & 1u)) >> 16;
  return (ushort)r;
}
static __device__ __forceinline__ half2_t u2h2(unsigned u) {
  union { unsigned u; half2_t h; } c; c.u = u; return c.h;
}
template <bool HI>
static __device__ __forceinline__ unsigned pk_fp8(float a, float b, unsigned old) {
  return (unsigned)__builtin_amdgcn_cvt_pk_fp8_f32(a, b, (int)old, HI);
}
template <bool HI>
static __device__ __forceinline__ vf2 fp8_f32(unsigned u) {
  return __builtin_amdgcn_cvt_pk_f32_fp8((int)u, HI);
}

// ---------------- kTW: one-time weight prep + idx->float (parallel, 256 blocks) -------
__global__ __launch_bounds__(256) void kTW(
    const float* __restrict__ W1, const float* __restrict__ W2, const float* __restrict__ W3,
    const float* __restrict__ b1, const float* __restrict__ b2, const float* __restrict__ b3,
    const float* __restrict__ Ww1, const float* __restrict__ Ww2, const float* __restrict__ Wout,
    const int* __restrict__ idx,
    unsigned* __restrict__ Ww2Pk, ushort* __restrict__ Wb,
    unsigned char* __restrict__ Woutb8,
    ushort* __restrict__ Wuvb, float* __restrict__ bcat, float* __restrict__ out_idx)
{
  const int t = threadIdx.x;
  const int g = blockIdx.x * 256 + t;
  const int G = gridDim.x * 256;

  if (blockIdx.x == 0) {
    // Ww2Pk[i*256 + r] = half2(Ww2[r][2i], Ww2[r][2i+1]);  t = r
#pragma unroll
    for (int i = 0; i < 8; ++i) {
      __half2 hp = __floats2half2_rn(Ww2[t * 16 + 2 * i], Ww2[t * 16 + 2 * i + 1]);
      Ww2Pk[i * 256 + t] = *(unsigned*)&hp;
    }
    if (t < 192) {
      float v;
      if (t < 32)      v = b1[t];
      else if (t < 64) v = b2[t - 32];
      else             v = b3[t - 64];
      bcat[t] = v;
    }
  }

  for (int e = g; e < 24576; e += G) {         // Wb: [mt<12][kt<4][lane<64][j<8]
    int j = e & 7, l = (e >> 3) & 63, kt = (e >> 9) & 3, mt = e >> 11;
    int row = mt * 16 + (l & 15);
    int k = kt * 32 + (l >> 4) * 8 + j;
    float v;
    if (row < 32)      v = W1[row * 128 + k];
    else if (row < 64) v = W2[(row - 32) * 128 + k];
    else               v = W3[(row - 64) * 128 + k];
    Wb[e] = f2bf(v);
  }
  // Woutb8: fp8 A-frags of Wout: [mt<8][kt<4][lane<64][j<8] bytes
  for (int e = g; e < 16384; e += G) {
    int j = e & 7, l = (e >> 3) & 63, kt = (e >> 9) & 3, mt = e >> 11;
    int row = mt * 16 + (l & 15);
    int k = kt * 32 + (l >> 4) * 8 + j;
    Woutb8[e] = (unsigned char)(pk_fp8<false>(Wout[row * 128 + k], 0.f, 0u) & 0xFFu);
  }
  // Wuvb: A-frags of Wuv[272][64]; row<16: u (x1 cols), row>=16: v[kk*16+m] (y2 cols)
  for (int e = g; e < 17408; e += G) {         // [mt<17][kt<2][lane<64][j<8]
    int j = e & 7, l = (e >> 3) & 63, kt = (e >> 9) & 1, mt = e >> 10;
    int row = mt * 16 + (l & 15);
    int k = kt * 32 + (l >> 4) * 8 + j;
    float v = 0.f;
    if (row < 16) {
      if (k < 32) v = Ww1[row * 544 + k];
    } else {
      if (k >= 32) {
        int rr = row - 16, kk = rr >> 4, m = rr & 15;
        v = Ww1[m * 544 + 32 + (k - 32) * 16 + kk];
      }
    }
    Wuvb[e] = f2bf(v);
  }
  // idx -> float output chunk
  for (int e = g; e < TOTPTS * 16; e += G)
    out_idx[e] = (float)idx[e];
}

// ---------------- kA2: fused [convs via MFMA] + [u,v via MFMA], fp8 outputs -----------
__global__ __launch_bounds__(256) void kA2(
    const float* __restrict__ x, const ushort* __restrict__ Wb,
    const ushort* __restrict__ Wuvb, const float* __restrict__ bcat,
    unsigned char* __restrict__ Yg, unsigned char* __restrict__ V)
{
  __shared__ __align__(16) char smem[44032];
  ushort* xB = (ushort*)smem;                        // phase 1-2
  unsigned char (*yst3)[136] = (unsigned char(*)[136])smem;  // phase 3-4: fp8 y3
  unsigned (*vst)[73] = (unsigned(*)[73])smem;       // phase 5-6: fp8 uv (68 data uints)
  ushort* uvB = (ushort*)(smem + 35840);             // phase 3-5: x1y2 bf16 B-frags

  const int t = threadIdx.x;
  const int blk = blockIdx.x;                   // 512
  const int b  = blk >> 7;
  const int n0 = (blk & 127) << 6;
  const float* xb = x + (size_t)b * 128 * NPTS;

#pragma unroll
  for (int i = 0; i < 32; ++i) {
    int e = t + 256 * i;                        // 8192 = 128 k * 64 pts
    int k = e >> 6, p = e & 63;
    float v = fmaxf(xb[(size_t)k * NPTS + n0 + p], 0.f);
    int lane = ((k & 31) >> 3) * 16 + (p & 15);
    int flat = (((p >> 4) * 4 + (k >> 5)) * 64 + lane) * 8 + (k & 7);
    xB[flat] = f2bf(v);
  }
  __syncthreads();

  const int w = t >> 6, l = t & 63;
  bf16x8 bfr[4];
#pragma unroll
  for (int kt = 0; kt < 4; ++kt)
    bfr[kt] = *reinterpret_cast<const bf16x8*>(&xB[((w * 4 + kt) * 64 + l) * 8]);
  __syncthreads();

  const int ptl = 16 * w + (l & 15);
  const int rbase = (l >> 4) * 4;
#pragma unroll
  for (int mt = 0; mt < 12; ++mt) {
    f32x4 acc = {0.f, 0.f, 0.f, 0.f};
#pragma unroll
    for (int kt = 0; kt < 4; ++kt) {
      bf16x8 a = *reinterpret_cast<const bf16x8*>(Wb + ((size_t)(mt * 4 + kt) * 64 + l) * 8);
      acc = __builtin_amdgcn_mfma_f32_16x16x32_bf16(a, bfr[kt], acc, 0, 0, 0);
    }
#pragma unroll
    for (int r = 0; r < 4; ++r) {
      int c = mt * 16 + rbase + r;
      float v = acc[r] + bcat[c];
      if (c < 64) {
        v = fmaxf(v, 0.f);
        int flat = (((ptl >> 4) * 2 + (c >> 5)) * 64
                    + ((c & 31) >> 3) * 16 + (ptl & 15)) * 8 + (c & 7);
        uvB[flat] = f2bf(v);
      } else {                                  // y3 -> fp8 byte, interleaved
        int cc = c - 64;
        int mc = (cc < 64) ? 2 * cc : 2 * (cc - 64) + 1;
        yst3[ptl][mc] = (unsigned char)(pk_fp8<false>(v, 0.f, 0u) & 0xFFu);
      }
    }
  }
  __syncthreads();

  // ---- store Yg (fp8): 32 uints / point ----
  {
    const unsigned* ys32 = (const unsigned*)yst3;   // pitch 34 uints
    unsigned* Yg32 = (unsigned*)(Yg + (size_t)(b * NPTS + n0) * 128);
#pragma unroll
    for (int i = 0; i < 8; ++i) {
      int e = t + 256 * i;                      // 2048 = 64 pts * 32 uints
      int p = e >> 5, cu = e & 31;
      Yg32[p * 32 + cu] = ys32[p * 34 + cu];
    }
  }
  __syncthreads();

  // ---- uv MFMAs (17 m-tiles x 2 k-steps) -> fp8 vst ----
  {
    bf16x8 ub[2];
#pragma unroll
    for (int kt = 0; kt < 2; ++kt)
      ub[kt] = *reinterpret_cast<const bf16x8*>(&uvB[((w * 2 + kt) * 64 + l) * 8]);
#pragma unroll
    for (int mt = 0; mt < 17; ++mt) {
      f32x4 acc = {0.f, 0.f, 0.f, 0.f};
#pragma unroll
      for (int kt = 0; kt < 2; ++kt) {
        bf16x8 a = *reinterpret_cast<const bf16x8*>(Wuvb + ((size_t)(mt * 2 + kt) * 64 + l) * 8);
        acc = __builtin_amdgcn_mfma_f32_16x16x32_bf16(a, ub[kt], acc, 0, 0, 0);
      }
      unsigned pk = pk_fp8<false>(acc[0], acc[1], 0u);
      pk = pk_fp8<true>(acc[2], acc[3], pk);
      vst[ptl][mt * 4 + (rbase >> 2)] = pk;
    }
  }
  __syncthreads();

  // ---- store V (fp8, 68 uints of 72-uint stride) ----
  {
    unsigned* V32 = (unsigned*)V;
    const int pt0g = b * NPTS + n0;
#pragma unroll
    for (int i = 0; i < 17; ++i) {
      int e = t + 256 * i;                      // 4352 = 64 * 68
      int p = e / 68, f = e - p * 68;
      V32[(size_t)(pt0g + p) * 72 + f] = vst[p][f];
    }
  }
}

// ---------------- kBC: fused gather+MLP+weighted-sum AND Wout GEMM + residual ---------
// 2048 blocks x 256 thr. Block owns 16 points; wave w4 owns pts w4*4..+3 (2 rounds x 2).
// Mid results -> fp8 LDS tile; kC phase: fp8 MFMA vs pre-packed Wout frags; direct store.
__global__ __launch_bounds__(256, 6) void kBC(
    const unsigned char* __restrict__ V, const unsigned char* __restrict__ Yg,
    const int* __restrict__ idx, const unsigned* __restrict__ Ww2Pk,
    const float* __restrict__ bw2,
    const unsigned char* __restrict__ Woutb8, const float* __restrict__ bout,
    const float* __restrict__ x, float* __restrict__ out)
{
  __shared__ unsigned w2s[2048];     // packed fp16 Ww2T pairs, 8 KB
  __shared__ unsigned hpk[4][20];    // [wave][p*8 + i], packed fp16 h
  __shared__ float wcs[4][2][292];   // per-wave, per-point transpose buffers
  __shared__ unsigned char mls[16][136];  // fp8 mid tile: [local pt][channel]

  const int t = threadIdx.x, l = t & 63;
  const int w4 = __builtin_amdgcn_readfirstlane(t >> 6);
  const int bid = blockIdx.x;                   // 2048
  const int xcd = bid & 7, bb = xcd >> 1;
  const int sb = ((bid >> 3) << 1) | (xcd & 1); // 0..511
  const int pt0 = bb * NPTS + sb * 16;
  const int bbase = bb * NPTS;
  const int kk = l >> 2, j = l & 3;

  // stage packed weights -> LDS (coalesced, 8 KB)
#pragma unroll
  for (int i = 0; i < 8; ++i) w2s[t + 256 * i] = Ww2Pk[t + 256 * i];

  const float2 bwa = *reinterpret_cast<const float2*>(bw2 + 2 * l);
  const float2 bwb = *reinterpret_cast<const float2*>(bw2 + 128 + 2 * l);
  const int q0 = l >> 3, g0 = (2 * l) & 15, g = l & 15;
  unsigned* hw = hpk[w4];

#pragma unroll
  for (int r = 0; r < 2; ++r) {
    const int pbase = pt0 + w4 * 4 + r * 2;
    const int* ip0 = idx + (size_t)pbase * 16;  // SGPR base (wave-uniform)

    // ---- issue ALL gathers upfront ----
    int nbv0 = ip0[kk], nbv1 = ip0[16 + kk];
    unsigned vr0 = *reinterpret_cast<const unsigned*>(
        V + (size_t)(bbase + nbv0) * VSTRB + 16 + kk * 16 + 4 * j);
    unsigned vr1 = *reinterpret_cast<const unsigned*>(
        V + (size_t)(bbase + nbv1) * VSTRB + 16 + kk * 16 + 4 * j);
    unsigned ur = 0u;
    if (kk < 2)
      ur = *reinterpret_cast<const unsigned*>(
          V + (size_t)(pbase + kk) * VSTRB + 4 * j);
    ushort y3a[16], y3b[16];
#pragma unroll
    for (int k2 = 0; k2 < 16; ++k2) {
      int nb = ip0[k2];
      y3a[k2] = *reinterpret_cast<const ushort*>(Yg + (size_t)(bbase + nb) * 128 + 2 * l);
    }
#pragma unroll
    for (int k2 = 0; k2 < 16; ++k2) {
      int nb = ip0[16 + k2];
      y3b[k2] = *reinterpret_cast<const ushort*>(Yg + (size_t)(bbase + nb) * 128 + 2 * l);
    }

    // ---- decode fp8 + f32 butterflies -> packed fp16 h in LDS ----
#pragma unroll
    for (int p = 0; p < 2; ++p) {
      unsigned vv = p ? vr1 : vr0;
      vf2 d01 = fp8_f32<false>(vv), d23 = fp8_f32<true>(vv);
      float h0 = d01.x, h1 = d01.y, h2 = d23.x, h3 = d23.y;
      if (kk == p) {
        vf2 u01 = fp8_f32<false>(ur), u23 = fp8_f32<true>(ur);
        h0 += u01.x; h1 += u01.y; h2 += u23.x; h3 += u23.y;
      }
#pragma unroll
      for (int s = 4; s < 64; s <<= 1) {
        h0 += __shfl_xor(h0, s);
        h1 += __shfl_xor(h1, s);
        h2 += __shfl_xor(h2, s);
        h3 += __shfl_xor(h3, s);
      }
      if (l < 4) {                              // j = l: owns h[4l..4l+3]
        __half2 a = __floats2half2_rn(fmaxf(h0, 0.f), fmaxf(h1, 0.f));
        __half2 b = __floats2half2_rn(fmaxf(h2, 0.f), fmaxf(h3, 0.f));
        hw[p * 8 + 2 * l]     = *(unsigned*)&a;
        hw[p * 8 + 2 * l + 1] = *(unsigned*)&b;
      }
    }
    // round 0: block barrier (w2s visibility); round 1: wave-private handoff
    asm volatile("s_waitcnt lgkmcnt(0)" ::: "memory");
    if (r == 0) __builtin_amdgcn_s_barrier();
    __builtin_amdgcn_sched_barrier(0);

    // h packed (broadcast LDS reads)
    half2_t hp0[8], hp1[8];
#pragma unroll
    for (int i = 0; i < 8; ++i) hp0[i] = u2h2(hw[i]);
#pragma unroll
    for (int i = 0; i < 8; ++i) hp1[i] = u2h2(hw[8 + i]);

    // wc for both points in ONE weight pass (weights from LDS)
    float4 wcv0 = {bwa.x, bwa.y, bwb.x, bwb.y};
    float4 wcv1 = wcv0;
#pragma unroll
    for (int i = 0; i < 8; ++i) {
      uint2 wa = *reinterpret_cast<const uint2*>(&w2s[i * 256 + 2 * l]);
      uint2 wb = *reinterpret_cast<const uint2*>(&w2s[i * 256 + 128 + 2 * l]);
      half2_t wax = u2h2(wa.x), way = u2h2(wa.y);
      half2_t wbx = u2h2(wb.x), wby = u2h2(wb.y);
      wcv0.x = __builtin_amdgcn_fdot2(wax, hp0[i], wcv0.x, false);
      wcv0.y = __builtin_amdgcn_fdot2(way, hp0[i], wcv0.y, false);
      wcv0.z = __builtin_amdgcn_fdot2(wbx, hp0[i], wcv0.z, false);
      wcv0.w = __builtin_amdgcn_fdot2(wby, hp0[i], wcv0.w, false);
      wcv1.x = __builtin_amdgcn_fdot2(wax, hp1[i], wcv1.x, false);
      wcv1.y = __builtin_amdgcn_fdot2(way, hp1[i], wcv1.y, false);
      wcv1.z = __builtin_amdgcn_fdot2(wbx, hp1[i], wcv1.z, false);
      wcv1.w = __builtin_amdgcn_fdot2(wby, hp1[i], wcv1.w, false);
    }

    // transpose stores (layout [mg][kk]: r = mg*16+kk -> slot mg*18+kk), ONE fence
    float* wr0 = wcs[w4][0];
    float* wr1 = wcs[w4][1];
    wr0[q0 * 18 + g0]           = wcv0.x;
    wr0[q0 * 18 + g0 + 1]       = wcv0.y;
    wr0[(q0 + 8) * 18 + g0]     = wcv0.z;
    wr0[(q0 + 8) * 18 + g0 + 1] = wcv0.w;
    wr1[q0 * 18 + g0]           = wcv1.x;
    wr1[q0 * 18 + g0 + 1]       = wcv1.y;
    wr1[(q0 + 8) * 18 + g0]     = wcv1.z;
    wr1[(q0 + 8) * 18 + g0 + 1] = wcv1.w;
    asm volatile("s_waitcnt lgkmcnt(0)" ::: "memory");
    __builtin_amdgcn_sched_barrier(0);

    float2 wrow0[8], wrow1[8];
#pragma unroll
    for (int qq = 0; qq < 8; ++qq) {
      wrow0[qq] = *reinterpret_cast<const float2*>(&wr0[g * 18 + 2 * qq]);
      wrow1[qq] = *reinterpret_cast<const float2*>(&wr1[g * 18 + 2 * qq]);
    }

    // mid[c] = relu(sum_k wc[(c%16)*16+k] * y3[k][c]); lane owns c = l, l+64
    float m0 = 0.f, m1 = 0.f, m2 = 0.f, m3 = 0.f;
#pragma unroll
    for (int k2 = 0; k2 < 16; ++k2) {
      float wc0 = (k2 & 1) ? wrow0[k2 >> 1].y : wrow0[k2 >> 1].x;
      float wc1 = (k2 & 1) ? wrow1[k2 >> 1].y : wrow1[k2 >> 1].x;
      vf2 ya = fp8_f32<false>((unsigned)y3a[k2]);
      vf2 yb = fp8_f32<false>((unsigned)y3b[k2]);
      m0 = fmaf(wc0, ya.x, m0);
      m1 = fmaf(wc0, ya.y, m1);
      m2 = fmaf(wc1, yb.x, m2);
      m3 = fmaf(wc1, yb.y, m3);
    }
    // write mid -> fp8 LDS tile (local pts w4*4 + r*2, +1)
    const int plo = w4 * 4 + r * 2;
    mls[plo][l]          = (unsigned char)(pk_fp8<false>(fmaxf(m0, 0.f), 0.f, 0u) & 0xFFu);
    mls[plo][64 + l]     = (unsigned char)(pk_fp8<false>(fmaxf(m1, 0.f), 0.f, 0u) & 0xFFu);
    mls[plo + 1][l]      = (unsigned char)(pk_fp8<false>(fmaxf(m2, 0.f), 0.f, 0u) & 0xFFu);
    mls[plo + 1][64 + l] = (unsigned char)(pk_fp8<false>(fmaxf(m3, 0.f), 0.f, 0u) & 0xFFu);
  }

  __syncthreads();                              // mls tile complete, all waves

  // ---- kC phase: out = Wout @ mid + bout + x via fp8 MFMA ----
  {
    const int rbase = (l >> 4) * 4;
    long bfr[4];
#pragma unroll
    for (int kt = 0; kt < 4; ++kt)
      bfr[kt] = *reinterpret_cast<const long*>(&mls[l & 15][kt * 32 + (l >> 4) * 8]);

#pragma unroll
    for (int mi = 0; mi < 2; ++mi) {
      const int mt = w4 * 2 + mi;
      f32x4 acc = {0.f, 0.f, 0.f, 0.f};
#pragma unroll
      for (int kt = 0; kt < 4; ++kt) {
        long a = *reinterpret_cast<const long*>(
            Woutb8 + ((size_t)(mt * 4 + kt) * 64 + l) * 8);
        acc = __builtin_amdgcn_mfma_f32_16x16x32_fp8_fp8(a, bfr[kt], acc, 0, 0, 0);
      }
#pragma unroll
      for (int r = 0; r < 4; ++r) {
        int c = mt * 16 + rbase + r;
        size_t gi = ((size_t)(bb * 128 + c)) * NPTS + sb * 16 + (l & 15);
        out[gi] = acc[r] + bout[c] + x[gi];
      }
    }
  }
}

extern "C" void kernel_launch(void* const* d_in, const int* in_sizes, int n_in,
                              void* d_out, int out_size, void* d_ws, size_t ws_size,
                              hipStream_t stream)
{
  const float* x    = (const float*)d_in[0];
  const int*   idx  = (const int*)  d_in[1];
  const float* W1   = (const float*)d_in[2];
  const float* b1   = (const float*)d_in[3];
  const float* W2   = (const float*)d_in[4];
  const float* b2   = (const float*)d_in[5];
  const float* W3   = (const float*)d_in[6];
  const float* b3   = (const float*)d_in[7];
  const float* Ww1  = (const float*)d_in[8];
  const float* Ww2  = (const float*)d_in[9];
  const float* bw2  = (const float*)d_in[10];
  const float* Wout = (const float*)d_in[11];
  const float* bout = (const float*)d_in[12];

  float* out     = (float*)d_out;
  float* out_idx = out + (size_t)NB * 128 * NPTS;

  char* wsp = (char*)d_ws;
  unsigned char* Yg = (unsigned char*)wsp; wsp += (size_t)TOTPTS * 128;   // 4.19 MB
  unsigned char* V  = (unsigned char*)wsp; wsp += (size_t)TOTPTS * VSTRB; // 9.44 MB
  unsigned* Ww2Pk = (unsigned*)wsp;        wsp += 2048 * 4;
  ushort* Wb      = (ushort*)wsp;          wsp += 24576 * 2;
  unsigned char* Woutb8 = (unsigned char*)wsp; wsp += 16384;
  ushort* Wuvb    = (ushort*)wsp;          wsp += 17408 * 2;
  float*  bcat    = (float*)wsp;           wsp += 192 * 4;

  kTW<<<256, 256, 0, stream>>>(W1, W2, W3, b1, b2, b3, Ww1, Ww2, Wout, idx,
                               Ww2Pk, Wb, Woutb8, Wuvb, bcat, out_idx);
  kA2<<<512, 256, 0, stream>>>(x, Wb, Wuvb, bcat, Yg, V);
  kBC<<<2048, 256, 0, stream>>>(V, Yg, idx, Ww2Pk, bw2, Woutb8, bout, x, out);
}

// Round 19
// 50.234 us; speedup vs baseline: 1.0145x; 1.0145x over previous
//
#include <hip/hip_runtime.h>
#include <hip/hip_fp16.h>

#define NPTS    8192
#define NB      4
#define TOTPTS  32768
#define VSTRB   288   // BYTES per point in V: [u(16B) | v(16+kk*16+m, 256B) | pad(16B)]
// Yg layout per point (128 fp8 bytes): byte 2c = y3[c], 2c+1 = y3[c+64]
// midb8 per point (128 fp8 bytes): byte c = mid channel c

typedef __attribute__((ext_vector_type(8))) short bf16x8;
typedef __attribute__((ext_vector_type(4))) float f32x4;
typedef __attribute__((ext_vector_type(2))) float vf2;
typedef _Float16 half2_t __attribute__((ext_vector_type(2)));

static __device__ __forceinline__ ushort f2bf(float f) {
  unsigned u = __float_as_uint(f);
  unsigned r = (u + 0x7FFFu + ((u >> 16) & 1u)) >> 16;
  return (ushort)r;
}
static __device__ __forceinline__ half2_t u2h2(unsigned u) {
  union { unsigned u; half2_t h; } c; c.u = u; return c.h;
}
template <bool HI>
static __device__ __forceinline__ unsigned pk_fp8(float a, float b, unsigned old) {
  return (unsigned)__builtin_amdgcn_cvt_pk_fp8_f32(a, b, (int)old, HI);
}
template <bool HI>
static __device__ __forceinline__ vf2 fp8_f32(unsigned u) {
  return __builtin_amdgcn_cvt_pk_f32_fp8((int)u, HI);
}

// ---------------- kTW: one-time weight prep (parallel, 64 blocks) ---------------------
__global__ __launch_bounds__(256) void kTW(
    const float* __restrict__ W1, const float* __restrict__ W2, const float* __restrict__ W3,
    const float* __restrict__ b1, const float* __restrict__ b2, const float* __restrict__ b3,
    const float* __restrict__ Ww1, const float* __restrict__ Ww2, const float* __restrict__ Wout,
    unsigned* __restrict__ Ww2Pk, ushort* __restrict__ Wb,
    unsigned char* __restrict__ Woutb8,
    ushort* __restrict__ Wuvb, float* __restrict__ bcat)
{
  const int t = threadIdx.x;
  const int g = blockIdx.x * 256 + t;
  const int G = gridDim.x * 256;

  if (blockIdx.x == 0) {
    // Ww2Pk[i*256 + r] = half2(Ww2[r][2i], Ww2[r][2i+1]);  t = r
#pragma unroll
    for (int i = 0; i < 8; ++i) {
      __half2 hp = __floats2half2_rn(Ww2[t * 16 + 2 * i], Ww2[t * 16 + 2 * i + 1]);
      Ww2Pk[i * 256 + t] = *(unsigned*)&hp;
    }
    if (t < 192) {
      float v;
      if (t < 32)      v = b1[t];
      else if (t < 64) v = b2[t - 32];
      else             v = b3[t - 64];
      bcat[t] = v;
    }
  }

  for (int e = g; e < 24576; e += G) {         // Wb: [mt<12][kt<4][lane<64][j<8]
    int j = e & 7, l = (e >> 3) & 63, kt = (e >> 9) & 3, mt = e >> 11;
    int row = mt * 16 + (l & 15);
    int k = kt * 32 + (l >> 4) * 8 + j;
    float v;
    if (row < 32)      v = W1[row * 128 + k];
    else if (row < 64) v = W2[(row - 32) * 128 + k];
    else               v = W3[(row - 64) * 128 + k];
    Wb[e] = f2bf(v);
  }
  // Woutb8: fp8 A-frags of Wout: [mt<8][kt<4][lane<64][j<8] bytes
  for (int e = g; e < 16384; e += G) {
    int j = e & 7, l = (e >> 3) & 63, kt = (e >> 9) & 3, mt = e >> 11;
    int row = mt * 16 + (l & 15);
    int k = kt * 32 + (l >> 4) * 8 + j;
    Woutb8[e] = (unsigned char)(pk_fp8<false>(Wout[row * 128 + k], 0.f, 0u) & 0xFFu);
  }
  // Wuvb: A-frags of Wuv[272][64]; row<16: u (x1 cols), row>=16: v[kk*16+m] (y2 cols)
  for (int e = g; e < 17408; e += G) {         // [mt<17][kt<2][lane<64][j<8]
    int j = e & 7, l = (e >> 3) & 63, kt = (e >> 9) & 1, mt = e >> 10;
    int row = mt * 16 + (l & 15);
    int k = kt * 32 + (l >> 4) * 8 + j;
    float v = 0.f;
    if (row < 16) {
      if (k < 32) v = Ww1[row * 544 + k];
    } else {
      if (k >= 32) {
        int rr = row - 16, kk = rr >> 4, m = rr & 15;
        v = Ww1[m * 544 + 32 + (k - 32) * 16 + kk];
      }
    }
    Wuvb[e] = f2bf(v);
  }
}

// ---------------- kA2: fused [convs via MFMA] + [u,v via MFMA], fp8 outputs -----------
__global__ __launch_bounds__(256) void kA2(
    const float* __restrict__ x, const ushort* __restrict__ Wb,
    const ushort* __restrict__ Wuvb, const float* __restrict__ bcat,
    unsigned char* __restrict__ Yg, unsigned char* __restrict__ V)
{
  __shared__ __align__(16) char smem[44032];
  ushort* xB = (ushort*)smem;
  unsigned char (*yst3)[136] = (unsigned char(*)[136])smem;
  unsigned (*vst)[73] = (unsigned(*)[73])smem;
  ushort* uvB = (ushort*)(smem + 35840);

  const int t = threadIdx.x;
  const int blk = blockIdx.x;                   // 512
  const int b  = blk >> 7;
  const int n0 = (blk & 127) << 6;
  const float* xb = x + (size_t)b * 128 * NPTS;

#pragma unroll
  for (int i = 0; i < 32; ++i) {
    int e = t + 256 * i;                        // 8192 = 128 k * 64 pts
    int k = e >> 6, p = e & 63;
    float v = fmaxf(xb[(size_t)k * NPTS + n0 + p], 0.f);
    int lane = ((k & 31) >> 3) * 16 + (p & 15);
    int flat = (((p >> 4) * 4 + (k >> 5)) * 64 + lane) * 8 + (k & 7);
    xB[flat] = f2bf(v);
  }
  __syncthreads();

  const int w = t >> 6, l = t & 63;
  bf16x8 bfr[4];
#pragma unroll
  for (int kt = 0; kt < 4; ++kt)
    bfr[kt] = *reinterpret_cast<const bf16x8*>(&xB[((w * 4 + kt) * 64 + l) * 8]);
  __syncthreads();

  const int ptl = 16 * w + (l & 15);
  const int rbase = (l >> 4) * 4;
#pragma unroll
  for (int mt = 0; mt < 12; ++mt) {
    f32x4 acc = {0.f, 0.f, 0.f, 0.f};
#pragma unroll
    for (int kt = 0; kt < 4; ++kt) {
      bf16x8 a = *reinterpret_cast<const bf16x8*>(Wb + ((size_t)(mt * 4 + kt) * 64 + l) * 8);
      acc = __builtin_amdgcn_mfma_f32_16x16x32_bf16(a, bfr[kt], acc, 0, 0, 0);
    }
#pragma unroll
    for (int r = 0; r < 4; ++r) {
      int c = mt * 16 + rbase + r;
      float v = acc[r] + bcat[c];
      if (c < 64) {
        v = fmaxf(v, 0.f);
        int flat = (((ptl >> 4) * 2 + (c >> 5)) * 64
                    + ((c & 31) >> 3) * 16 + (ptl & 15)) * 8 + (c & 7);
        uvB[flat] = f2bf(v);
      } else {                                  // y3 -> fp8 byte, interleaved
        int cc = c - 64;
        int mc = (cc < 64) ? 2 * cc : 2 * (cc - 64) + 1;
        yst3[ptl][mc] = (unsigned char)(pk_fp8<false>(v, 0.f, 0u) & 0xFFu);
      }
    }
  }
  __syncthreads();

  {
    const unsigned* ys32 = (const unsigned*)yst3;   // pitch 34 uints
    unsigned* Yg32 = (unsigned*)(Yg + (size_t)(b * NPTS + n0) * 128);
#pragma unroll
    for (int i = 0; i < 8; ++i) {
      int e = t + 256 * i;                      // 2048 = 64 pts * 32 uints
      int p = e >> 5, cu = e & 31;
      Yg32[p * 32 + cu] = ys32[p * 34 + cu];
    }
  }
  __syncthreads();

  {
    bf16x8 ub[2];
#pragma unroll
    for (int kt = 0; kt < 2; ++kt)
      ub[kt] = *reinterpret_cast<const bf16x8*>(&uvB[((w * 2 + kt) * 64 + l) * 8]);
#pragma unroll
    for (int mt = 0; mt < 17; ++mt) {
      f32x4 acc = {0.f, 0.f, 0.f, 0.f};
#pragma unroll
      for (int kt = 0; kt < 2; ++kt) {
        bf16x8 a = *reinterpret_cast<const bf16x8*>(Wuvb + ((size_t)(mt * 2 + kt) * 64 + l) * 8);
        acc = __builtin_amdgcn_mfma_f32_16x16x32_bf16(a, ub[kt], acc, 0, 0, 0);
      }
      unsigned pk = pk_fp8<false>(acc[0], acc[1], 0u);
      pk = pk_fp8<true>(acc[2], acc[3], pk);
      vst[ptl][mt * 4 + (rbase >> 2)] = pk;
    }
  }
  __syncthreads();

  {
    unsigned* V32 = (unsigned*)V;
    const int pt0g = b * NPTS + n0;
#pragma unroll
    for (int i = 0; i < 17; ++i) {
      int e = t + 256 * i;                      // 4352 = 64 * 68
      int p = e / 68, f = e - p * 68;
      V32[(size_t)(pt0g + p) * 72 + f] = vst[p][f];
    }
  }
}

// ---------------- kB: gather + attention weights + weighted sum (fp8) -----------------
__global__ __launch_bounds__(256, 6) void kB(
    const unsigned char* __restrict__ V, const unsigned char* __restrict__ Yg,
    const int* __restrict__ idx, const unsigned* __restrict__ Ww2Pk,
    const float* __restrict__ bw2, unsigned char* __restrict__ midb8,
    float* __restrict__ out_idx)
{
  __shared__ unsigned w2s[2048];     // packed fp16 Ww2T pairs, 8 KB
  __shared__ unsigned hpk[4][20];    // [wave][p*8 + i], packed fp16 h
  __shared__ float wcs[4][2][292];   // per-wave, per-point transpose buffers

  const int t = threadIdx.x, l = t & 63;
  const int w4 = __builtin_amdgcn_readfirstlane(t >> 6);
  const int bid = blockIdx.x;                   // 4096
  const int xcd = bid & 7, bb = xcd >> 1;
  const int sb = ((bid >> 3) << 1) | (xcd & 1); // 0..1023
  const int pbase = bb * NPTS + sb * 8 + w4 * 2;
  const int bbase = bb * NPTS;
  const int kk = l >> 2, j = l & 3;

  // stage packed weights -> LDS (coalesced, 8 KB)
#pragma unroll
  for (int i = 0; i < 8; ++i) w2s[t + 256 * i] = Ww2Pk[t + 256 * i];

  const int* ip0 = idx + (size_t)pbase * 16;    // SGPR base (wave-uniform)

  // fused idx -> float output (both points' rows)
  {
    int iv = idx[(size_t)pbase * 16 + (l & 31)];
    if (l < 32) out_idx[(size_t)pbase * 16 + l] = (float)iv;
  }

  // ---- issue ALL gathers upfront ----
  int nbv0 = ip0[kk], nbv1 = ip0[16 + kk];
  unsigned vr0 = *reinterpret_cast<const unsigned*>(
      V + (size_t)(bbase + nbv0) * VSTRB + 16 + kk * 16 + 4 * j);
  unsigned vr1 = *reinterpret_cast<const unsigned*>(
      V + (size_t)(bbase + nbv1) * VSTRB + 16 + kk * 16 + 4 * j);
  unsigned ur = 0u;
  if (kk < 2)
    ur = *reinterpret_cast<const unsigned*>(
        V + (size_t)(pbase + kk) * VSTRB + 4 * j);
  const float2 bwa = *reinterpret_cast<const float2*>(bw2 + 2 * l);
  const float2 bwb = *reinterpret_cast<const float2*>(bw2 + 128 + 2 * l);
  ushort y3a[16], y3b[16];
#pragma unroll
  for (int k2 = 0; k2 < 16; ++k2) {
    int nb = ip0[k2];
    y3a[k2] = *reinterpret_cast<const ushort*>(Yg + (size_t)(bbase + nb) * 128 + 2 * l);
  }
#pragma unroll
  for (int k2 = 0; k2 < 16; ++k2) {
    int nb = ip0[16 + k2];
    y3b[k2] = *reinterpret_cast<const ushort*>(Yg + (size_t)(bbase + nb) * 128 + 2 * l);
  }

  unsigned* hw = hpk[w4];

  // ---- decode fp8 + f32 butterflies -> packed fp16 h in LDS ----
#pragma unroll
  for (int p = 0; p < 2; ++p) {
    unsigned vv = p ? vr1 : vr0;
    vf2 d01 = fp8_f32<false>(vv), d23 = fp8_f32<true>(vv);
    float h0 = d01.x, h1 = d01.y, h2 = d23.x, h3 = d23.y;
    if (kk == p) {
      vf2 u01 = fp8_f32<false>(ur), u23 = fp8_f32<true>(ur);
      h0 += u01.x; h1 += u01.y; h2 += u23.x; h3 += u23.y;
    }
#pragma unroll
    for (int s = 4; s < 64; s <<= 1) {
      h0 += __shfl_xor(h0, s);
      h1 += __shfl_xor(h1, s);
      h2 += __shfl_xor(h2, s);
      h3 += __shfl_xor(h3, s);
    }
    if (l < 4) {                                // j = l: owns h[4l..4l+3]
      __half2 a = __floats2half2_rn(fmaxf(h0, 0.f), fmaxf(h1, 0.f));
      __half2 b = __floats2half2_rn(fmaxf(h2, 0.f), fmaxf(h3, 0.f));
      hw[p * 8 + 2 * l]     = *(unsigned*)&a;
      hw[p * 8 + 2 * l + 1] = *(unsigned*)&b;
    }
  }
  // LDS-only barrier: w2s + hpk visible, VMEM gathers stay in flight
  asm volatile("s_waitcnt lgkmcnt(0)" ::: "memory");
  __builtin_amdgcn_s_barrier();
  __builtin_amdgcn_sched_barrier(0);

  const int q0 = l >> 3, g0 = (2 * l) & 15, g = l & 15;

  half2_t hp0[8], hp1[8];
#pragma unroll
  for (int i = 0; i < 8; ++i) hp0[i] = u2h2(hw[i]);
#pragma unroll
  for (int i = 0; i < 8; ++i) hp1[i] = u2h2(hw[8 + i]);

  // wc for both points in ONE weight pass (weights from LDS)
  float4 wcv0 = {bwa.x, bwa.y, bwb.x, bwb.y};
  float4 wcv1 = wcv0;
#pragma unroll
  for (int i = 0; i < 8; ++i) {
    uint2 wa = *reinterpret_cast<const uint2*>(&w2s[i * 256 + 2 * l]);
    uint2 wb = *reinterpret_cast<const uint2*>(&w2s[i * 256 + 128 + 2 * l]);
    half2_t wax = u2h2(wa.x), way = u2h2(wa.y);
    half2_t wbx = u2h2(wb.x), wby = u2h2(wb.y);
    wcv0.x = __builtin_amdgcn_fdot2(wax, hp0[i], wcv0.x, false);
    wcv0.y = __builtin_amdgcn_fdot2(way, hp0[i], wcv0.y, false);
    wcv0.z = __builtin_amdgcn_fdot2(wbx, hp0[i], wcv0.z, false);
    wcv0.w = __builtin_amdgcn_fdot2(wby, hp0[i], wcv0.w, false);
    wcv1.x = __builtin_amdgcn_fdot2(wax, hp1[i], wcv1.x, false);
    wcv1.y = __builtin_amdgcn_fdot2(way, hp1[i], wcv1.y, false);
    wcv1.z = __builtin_amdgcn_fdot2(wbx, hp1[i], wcv1.z, false);
    wcv1.w = __builtin_amdgcn_fdot2(wby, hp1[i], wcv1.w, false);
  }

  // transpose stores (layout [mg][kk]: r = mg*16+kk -> slot mg*18+kk), ONE fence
  float* wr0 = wcs[w4][0];
  float* wr1 = wcs[w4][1];
  wr0[q0 * 18 + g0]           = wcv0.x;
  wr0[q0 * 18 + g0 + 1]       = wcv0.y;
  wr0[(q0 + 8) * 18 + g0]     = wcv0.z;
  wr0[(q0 + 8) * 18 + g0 + 1] = wcv0.w;
  wr1[q0 * 18 + g0]           = wcv1.x;
  wr1[q0 * 18 + g0 + 1]       = wcv1.y;
  wr1[(q0 + 8) * 18 + g0]     = wcv1.z;
  wr1[(q0 + 8) * 18 + g0 + 1] = wcv1.w;
  asm volatile("s_waitcnt lgkmcnt(0)" ::: "memory");
  __builtin_amdgcn_sched_barrier(0);

  float2 wrow0[8], wrow1[8];
#pragma unroll
  for (int qq = 0; qq < 8; ++qq) {
    wrow0[qq] = *reinterpret_cast<const float2*>(&wr0[g * 18 + 2 * qq]);
    wrow1[qq] = *reinterpret_cast<const float2*>(&wr1[g * 18 + 2 * qq]);
  }

  // mid[c] = relu(sum_k wc[(c%16)*16+k] * y3[k][c]); lane owns c = l, l+64
  float m0 = 0.f, m1 = 0.f, m2 = 0.f, m3 = 0.f;
#pragma unroll
  for (int k2 = 0; k2 < 16; ++k2) {
    float wc0 = (k2 & 1) ? wrow0[k2 >> 1].y : wrow0[k2 >> 1].x;
    float wc1 = (k2 & 1) ? wrow1[k2 >> 1].y : wrow1[k2 >> 1].x;
    vf2 ya = fp8_f32<false>((unsigned)y3a[k2]);
    vf2 yb = fp8_f32<false>((unsigned)y3b[k2]);
    m0 = fmaf(wc0, ya.x, m0);
    m1 = fmaf(wc0, ya.y, m1);
    m2 = fmaf(wc1, yb.x, m2);
    m3 = fmaf(wc1, yb.y, m3);
  }
  midb8[(size_t)pbase * 128 + l]            = (unsigned char)(pk_fp8<false>(fmaxf(m0, 0.f), 0.f, 0u) & 0xFFu);
  midb8[(size_t)pbase * 128 + 64 + l]       = (unsigned char)(pk_fp8<false>(fmaxf(m1, 0.f), 0.f, 0u) & 0xFFu);
  midb8[(size_t)(pbase + 1) * 128 + l]      = (unsigned char)(pk_fp8<false>(fmaxf(m2, 0.f), 0.f, 0u) & 0xFFu);
  midb8[(size_t)(pbase + 1) * 128 + 64 + l] = (unsigned char)(pk_fp8<false>(fmaxf(m3, 0.f), 0.f, 0u) & 0xFFu);
}

// ---------------- kC: out = Wout @ mid + bout + x, fp8 MFMA ---------------------------
__global__ __launch_bounds__(256) void kC(
    const unsigned char* __restrict__ midb8, const unsigned char* __restrict__ Woutb8,
    const float* __restrict__ bout,
    const float* __restrict__ x, float* __restrict__ out)
{
  __shared__ unsigned char blds[8192];          // fp8 B-frags [w<4][kt<4][lane<64][8]
  __shared__ float ml[128][68];

  const int t = threadIdx.x;
  const int pt0 = blockIdx.x << 6;
  const int b  = pt0 >> 13;
  const int n0 = pt0 & (NPTS - 1);

  const unsigned* mid32 = (const unsigned*)midb8;
  unsigned* blds32 = (unsigned*)blds;
#pragma unroll
  for (int i = 0; i < 8; ++i) {
    int e = t + 256 * i;                        // 2048 uints = 64 pts * 32 uints
    int p = e >> 5, cu = e & 31;
    unsigned val = mid32[(size_t)(pt0 + p) * 32 + cu];
    int fl = ((((p >> 4) * 4 + (cu >> 3)) * 64
               + ((cu & 7) >> 1) * 16 + (p & 15)) << 1) + (cu & 1);
    blds32[fl] = val;
  }
  __syncthreads();

  const int w = t >> 6, l = t & 63;
  long bfr[4];
#pragma unroll
  for (int kt = 0; kt < 4; ++kt)
    bfr[kt] = *reinterpret_cast<const long*>(&blds[((w * 4 + kt) * 64 + l) * 8]);

  const int rbase = (l >> 4) * 4;
  const int pl = 16 * w + (l & 15);
#pragma unroll
  for (int mt = 0; mt < 8; ++mt) {
    f32x4 acc = {0.f, 0.f, 0.f, 0.f};
#pragma unroll
    for (int kt = 0; kt < 4; ++kt) {
      long a = *reinterpret_cast<const long*>(
          Woutb8 + ((size_t)(mt * 4 + kt) * 64 + l) * 8);
      acc = __builtin_amdgcn_mfma_f32_16x16x32_fp8_fp8(a, bfr[kt], acc, 0, 0, 0);
    }
#pragma unroll
    for (int r = 0; r < 4; ++r)
      ml[mt * 16 + rbase + r][pl] = acc[r];
  }
  __syncthreads();

  for (int e = t; e < 8192; e += 256) {
    int c = e >> 6, p = e & 63;
    size_t gi = (size_t)(b * 128 + c) * NPTS + n0 + p;
    out[gi] = ml[c][p] + bout[c] + x[gi];
  }
}

extern "C" void kernel_launch(void* const* d_in, const int* in_sizes, int n_in,
                              void* d_out, int out_size, void* d_ws, size_t ws_size,
                              hipStream_t stream)
{
  const float* x    = (const float*)d_in[0];
  const int*   idx  = (const int*)  d_in[1];
  const float* W1   = (const float*)d_in[2];
  const float* b1   = (const float*)d_in[3];
  const float* W2   = (const float*)d_in[4];
  const float* b2   = (const float*)d_in[5];
  const float* W3   = (const float*)d_in[6];
  const float* b3   = (const float*)d_in[7];
  const float* Ww1  = (const float*)d_in[8];
  const float* Ww2  = (const float*)d_in[9];
  const float* bw2  = (const float*)d_in[10];
  const float* Wout = (const float*)d_in[11];
  const float* bout = (const float*)d_in[12];

  float* out     = (float*)d_out;
  float* out_idx = out + (size_t)NB * 128 * NPTS;

  char* wsp = (char*)d_ws;
  unsigned char* Yg    = (unsigned char*)wsp; wsp += (size_t)TOTPTS * 128;   // 4.19 MB
  unsigned char* V     = (unsigned char*)wsp; wsp += (size_t)TOTPTS * VSTRB; // 9.44 MB
  unsigned char* midb8 = (unsigned char*)wsp; wsp += (size_t)TOTPTS * 128;   // 4.19 MB
  unsigned* Ww2Pk = (unsigned*)wsp;           wsp += 2048 * 4;
  ushort* Wb      = (ushort*)wsp;             wsp += 24576 * 2;
  unsigned char* Woutb8 = (unsigned char*)wsp; wsp += 16384;
  ushort* Wuvb    = (ushort*)wsp;             wsp += 17408 * 2;
  float*  bcat    = (float*)wsp;              wsp += 192 * 4;

  kTW<<<64,  256, 0, stream>>>(W1, W2, W3, b1, b2, b3, Ww1, Ww2, Wout,
                               Ww2Pk, Wb, Woutb8, Wuvb, bcat);
  kA2<<<512, 256, 0, stream>>>(x, Wb, Wuvb, bcat, Yg, V);
  kB<<<4096, 256, 0, stream>>>(V, Yg, idx, Ww2Pk, bw2, midb8, out_idx);
  kC<<<512,  256, 0, stream>>>(midb8, Woutb8, bout, x, out);
}

// Round 20
// 47.474 us; speedup vs baseline: 1.0734x; 1.0581x over previous
//
#include <hip/hip_runtime.h>
#include <hip/hip_fp16.h>

#define NPTS    8192
#define NB      4
#define TOTPTS  32768
#define VSTRB   288   // BYTES per point in V: [u(16B) | v(16+kk*16+m, 256B) | pad(16B)]
// Yg layout per point (128 fp8 bytes): byte 2c = y3[c], 2c+1 = y3[c+64]

typedef __attribute__((ext_vector_type(8))) short bf16x8;
typedef __attribute__((ext_vector_type(4))) float f32x4;
typedef __attribute__((ext_vector_type(2))) float vf2;
typedef _Float16 half2_t __attribute__((ext_vector_type(2)));

static __device__ __forceinline__ ushort f2bf(float f) {
  unsigned u = __float_as_uint(f);
  unsigned r = (u + 0x7FFFu + ((u >> 16) & 1u)) >> 16;
  return (ushort)r;
}
static __device__ __forceinline__ half2_t u2h2(unsigned u) {
  union { unsigned u; half2_t h; } c; c.u = u; return c.h;
}
template <bool HI>
static __device__ __forceinline__ unsigned pk_fp8(float a, float b, unsigned old) {
  return (unsigned)__builtin_amdgcn_cvt_pk_fp8_f32(a, b, (int)old, HI);
}
template <bool HI>
static __device__ __forceinline__ vf2 fp8_f32(unsigned u) {
  return __builtin_amdgcn_cvt_pk_f32_fp8((int)u, HI);
}

// ---------------- kTW: one-time weight prep + idx->float (parallel, 256 blocks) -------
__global__ __launch_bounds__(256) void kTW(
    const float* __restrict__ W1, const float* __restrict__ W2, const float* __restrict__ W3,
    const float* __restrict__ b1, const float* __restrict__ b2, const float* __restrict__ b3,
    const float* __restrict__ Ww1, const float* __restrict__ Ww2, const float* __restrict__ Wout,
    const int* __restrict__ idx,
    unsigned* __restrict__ Ww2Pk, ushort* __restrict__ Wb, ushort* __restrict__ Woutb,
    ushort* __restrict__ Wuvb, float* __restrict__ bcat, float* __restrict__ out_idx)
{
  const int t = threadIdx.x;
  const int g = blockIdx.x * 256 + t;
  const int G = gridDim.x * 256;

  if (blockIdx.x == 0) {
    // Ww2Pk[i*256 + r] = half2(Ww2[r][2i], Ww2[r][2i+1]);  t = r
#pragma unroll
    for (int i = 0; i < 8; ++i) {
      __half2 hp = __floats2half2_rn(Ww2[t * 16 + 2 * i], Ww2[t * 16 + 2 * i + 1]);
      Ww2Pk[i * 256 + t] = *(unsigned*)&hp;
    }
    if (t < 192) {
      float v;
      if (t < 32)      v = b1[t];
      else if (t < 64) v = b2[t - 32];
      else             v = b3[t - 64];
      bcat[t] = v;
    }
  }

  for (int e = g; e < 24576; e += G) {         // Wb: [mt<12][kt<4][lane<64][j<8]
    int j = e & 7, l = (e >> 3) & 63, kt = (e >> 9) & 3, mt = e >> 11;
    int row = mt * 16 + (l & 15);
    int k = kt * 32 + (l >> 4) * 8 + j;
    float v;
    if (row < 32)      v = W1[row * 128 + k];
    else if (row < 64) v = W2[(row - 32) * 128 + k];
    else               v = W3[(row - 64) * 128 + k];
    Wb[e] = f2bf(v);
  }
  for (int e = g; e < 16384; e += G) {         // Woutb: [mt<8][kt<4][lane<64][j<8]
    int j = e & 7, l = (e >> 3) & 63, kt = (e >> 9) & 3, mt = e >> 11;
    int row = mt * 16 + (l & 15);
    int k = kt * 32 + (l >> 4) * 8 + j;
    Woutb[e] = f2bf(Wout[row * 128 + k]);
  }
  // Wuvb: A-frags of Wuv[272][64]; row<16: u (x1 cols), row>=16: v[kk*16+m] (y2 cols)
  for (int e = g; e < 17408; e += G) {         // [mt<17][kt<2][lane<64][j<8]
    int j = e & 7, l = (e >> 3) & 63, kt = (e >> 9) & 1, mt = e >> 10;
    int row = mt * 16 + (l & 15);
    int k = kt * 32 + (l >> 4) * 8 + j;
    float v = 0.f;
    if (row < 16) {
      if (k < 32) v = Ww1[row * 544 + k];
    } else {
      if (k >= 32) {
        int rr = row - 16, kk = rr >> 4, m = rr & 15;
        v = Ww1[m * 544 + 32 + (k - 32) * 16 + kk];
      }
    }
    Wuvb[e] = f2bf(v);
  }
  // idx -> float output chunk
  for (int e = g; e < TOTPTS * 16; e += G)
    out_idx[e] = (float)idx[e];
}

// ---------------- kA2: fused [convs via MFMA] + [u,v via MFMA], fp8 outputs -----------
// XCD-aligned: batch b handled by XCD pair {2b,2b+1} (matches kB's consumer mapping)
__global__ __launch_bounds__(256) void kA2(
    const float* __restrict__ x, const ushort* __restrict__ Wb,
    const ushort* __restrict__ Wuvb, const float* __restrict__ bcat,
    unsigned char* __restrict__ Yg, unsigned char* __restrict__ V)
{
  __shared__ __align__(16) char smem[44032];
  ushort* xB = (ushort*)smem;                        // phase 1-2
  unsigned char (*yst3)[136] = (unsigned char(*)[136])smem;  // phase 3-4: fp8 y3
  unsigned (*vst)[73] = (unsigned(*)[73])smem;       // phase 5-6: fp8 uv (68 data uints)
  ushort* uvB = (ushort*)(smem + 35840);             // phase 3-5: x1y2 bf16 B-frags

  const int t = threadIdx.x;
  const int blk = blockIdx.x;                   // 512
  const int xcd = blk & 7;
  const int b  = xcd >> 1;                      // batch -> XCD pair {2b,2b+1}
  const int n0 = (((blk >> 3) << 1) | (xcd & 1)) << 6;
  const float* xb = x + (size_t)b * 128 * NPTS;

#pragma unroll
  for (int i = 0; i < 32; ++i) {
    int e = t + 256 * i;                        // 8192 = 128 k * 64 pts
    int k = e >> 6, p = e & 63;
    float v = fmaxf(xb[(size_t)k * NPTS + n0 + p], 0.f);
    int lane = ((k & 31) >> 3) * 16 + (p & 15);
    int flat = (((p >> 4) * 4 + (k >> 5)) * 64 + lane) * 8 + (k & 7);
    xB[flat] = f2bf(v);
  }
  __syncthreads();

  const int w = t >> 6, l = t & 63;
  bf16x8 bfr[4];
#pragma unroll
  for (int kt = 0; kt < 4; ++kt)
    bfr[kt] = *reinterpret_cast<const bf16x8*>(&xB[((w * 4 + kt) * 64 + l) * 8]);
  __syncthreads();

  const int ptl = 16 * w + (l & 15);
  const int rbase = (l >> 4) * 4;
#pragma unroll
  for (int mt = 0; mt < 12; ++mt) {
    f32x4 acc = {0.f, 0.f, 0.f, 0.f};
#pragma unroll
    for (int kt = 0; kt < 4; ++kt) {
      bf16x8 a = *reinterpret_cast<const bf16x8*>(Wb + ((size_t)(mt * 4 + kt) * 64 + l) * 8);
      acc = __builtin_amdgcn_mfma_f32_16x16x32_bf16(a, bfr[kt], acc, 0, 0, 0);
    }
#pragma unroll
    for (int r = 0; r < 4; ++r) {
      int c = mt * 16 + rbase + r;
      float v = acc[r] + bcat[c];
      if (c < 64) {
        v = fmaxf(v, 0.f);
        int flat = (((ptl >> 4) * 2 + (c >> 5)) * 64
                    + ((c & 31) >> 3) * 16 + (ptl & 15)) * 8 + (c & 7);
        uvB[flat] = f2bf(v);
      } else {                                  // y3 -> fp8 byte, interleaved
        int cc = c - 64;
        int mc = (cc < 64) ? 2 * cc : 2 * (cc - 64) + 1;
        yst3[ptl][mc] = (unsigned char)(pk_fp8<false>(v, 0.f, 0u) & 0xFFu);
      }
    }
  }
  __syncthreads();

  // ---- store Yg (fp8): 32 uints / point ----
  {
    const unsigned* ys32 = (const unsigned*)yst3;   // pitch 34 uints
    unsigned* Yg32 = (unsigned*)(Yg + (size_t)(b * NPTS + n0) * 128);
#pragma unroll
    for (int i = 0; i < 8; ++i) {
      int e = t + 256 * i;                      // 2048 = 64 pts * 32 uints
      int p = e >> 5, cu = e & 31;
      Yg32[p * 32 + cu] = ys32[p * 34 + cu];
    }
  }
  __syncthreads();

  // ---- uv MFMAs (17 m-tiles x 2 k-steps) -> fp8 vst ----
  {
    bf16x8 ub[2];
#pragma unroll
    for (int kt = 0; kt < 2; ++kt)
      ub[kt] = *reinterpret_cast<const bf16x8*>(&uvB[((w * 2 + kt) * 64 + l) * 8]);
#pragma unroll
    for (int mt = 0; mt < 17; ++mt) {
      f32x4 acc = {0.f, 0.f, 0.f, 0.f};
#pragma unroll
      for (int kt = 0; kt < 2; ++kt) {
        bf16x8 a = *reinterpret_cast<const bf16x8*>(Wuvb + ((size_t)(mt * 2 + kt) * 64 + l) * 8);
        acc = __builtin_amdgcn_mfma_f32_16x16x32_bf16(a, ub[kt], acc, 0, 0, 0);
      }
      unsigned pk = pk_fp8<false>(acc[0], acc[1], 0u);
      pk = pk_fp8<true>(acc[2], acc[3], pk);
      vst[ptl][mt * 4 + (rbase >> 2)] = pk;
    }
  }
  __syncthreads();

  // ---- store V (fp8, 68 uints of 72-uint stride) ----
  {
    unsigned* V32 = (unsigned*)V;
    const int pt0g = b * NPTS + n0;
#pragma unroll
    for (int i = 0; i < 17; ++i) {
      int e = t + 256 * i;                      // 4352 = 64 * 68
      int p = e / 68, f = e - p * 68;
      V32[(size_t)(pt0g + p) * 72 + f] = vst[p][f];
    }
  }
}

// ---------------- kB: gather + attention weights + weighted sum (fp8 gathers) ---------
__global__ __launch_bounds__(256, 6) void kB(
    const unsigned char* __restrict__ V, const unsigned char* __restrict__ Yg,
    const int* __restrict__ idx, const unsigned* __restrict__ Ww2Pk,
    const float* __restrict__ bw2, ushort* __restrict__ midb)
{
  __shared__ unsigned w2s[2048];     // packed fp16 Ww2T pairs, 8 KB
  __shared__ unsigned hpk[4][20];    // [wave][p*8 + i], packed fp16 h
  __shared__ float wcs[4][2][292];   // per-wave, per-point transpose buffers

  const int t = threadIdx.x, l = t & 63;
  const int w4 = __builtin_amdgcn_readfirstlane(t >> 6);
  const int bid = blockIdx.x;                   // 4096
  const int xcd = bid & 7, bb = xcd >> 1;
  const int sb = ((bid >> 3) << 1) | (xcd & 1); // 0..1023
  const int pbase = bb * NPTS + sb * 8 + w4 * 2;
  const int bbase = bb * NPTS;
  const int kk = l >> 2, j = l & 3;

  // stage packed weights -> LDS (coalesced, 8 KB)
#pragma unroll
  for (int i = 0; i < 8; ++i) w2s[t + 256 * i] = Ww2Pk[t + 256 * i];

  const int* ip0 = idx + (size_t)pbase * 16;    // SGPR base (wave-uniform)

  // ---- issue ALL gathers upfront (stay in flight under butterfly+wc) ----
  int nbv0 = ip0[kk], nbv1 = ip0[16 + kk];
  unsigned vr0 = *reinterpret_cast<const unsigned*>(
      V + (size_t)(bbase + nbv0) * VSTRB + 16 + kk * 16 + 4 * j);
  unsigned vr1 = *reinterpret_cast<const unsigned*>(
      V + (size_t)(bbase + nbv1) * VSTRB + 16 + kk * 16 + 4 * j);
  unsigned ur = 0u;
  if (kk < 2)
    ur = *reinterpret_cast<const unsigned*>(
        V + (size_t)(pbase + kk) * VSTRB + 4 * j);
  const float2 bwa = *reinterpret_cast<const float2*>(bw2 + 2 * l);
  const float2 bwb = *reinterpret_cast<const float2*>(bw2 + 128 + 2 * l);
  ushort y3a[16], y3b[16];
#pragma unroll
  for (int k2 = 0; k2 < 16; ++k2) {
    int nb = ip0[k2];                           // wave-uniform scalar load
    y3a[k2] = *reinterpret_cast<const ushort*>(Yg + (size_t)(bbase + nb) * 128 + 2 * l);
  }
#pragma unroll
  for (int k2 = 0; k2 < 16; ++k2) {
    int nb = ip0[16 + k2];
    y3b[k2] = *reinterpret_cast<const ushort*>(Yg + (size_t)(bbase + nb) * 128 + 2 * l);
  }

  unsigned* hw = hpk[w4];

  // ---- decode fp8 + f32 butterflies -> packed fp16 h in LDS ----
#pragma unroll
  for (int p = 0; p < 2; ++p) {
    unsigned vv = p ? vr1 : vr0;
    vf2 d01 = fp8_f32<false>(vv), d23 = fp8_f32<true>(vv);
    float h0 = d01.x, h1 = d01.y, h2 = d23.x, h3 = d23.y;
    if (kk == p) {
      vf2 u01 = fp8_f32<false>(ur), u23 = fp8_f32<true>(ur);
      h0 += u01.x; h1 += u01.y; h2 += u23.x; h3 += u23.y;
    }
#pragma unroll
    for (int s = 4; s < 64; s <<= 1) {
      h0 += __shfl_xor(h0, s);
      h1 += __shfl_xor(h1, s);
      h2 += __shfl_xor(h2, s);
      h3 += __shfl_xor(h3, s);
    }
    if (l < 4) {                                // j = l: owns h[4l..4l+3]
      __half2 a = __floats2half2_rn(fmaxf(h0, 0.f), fmaxf(h1, 0.f));
      __half2 b = __floats2half2_rn(fmaxf(h2, 0.f), fmaxf(h3, 0.f));
      hw[p * 8 + 2 * l]     = *(unsigned*)&a;   // (h[4l],   h[4l+1])
      hw[p * 8 + 2 * l + 1] = *(unsigned*)&b;   // (h[4l+2], h[4l+3])
    }
  }
  // LDS-only barrier: w2s + hpk visible, VMEM gathers stay in flight
  asm volatile("s_waitcnt lgkmcnt(0)" ::: "memory");
  __builtin_amdgcn_s_barrier();
  __builtin_amdgcn_sched_barrier(0);

  const int q0 = l >> 3, g0 = (2 * l) & 15, g = l & 15;

  // h packed (broadcast LDS reads)
  half2_t hp0[8], hp1[8];
#pragma unroll
  for (int i = 0; i < 8; ++i) hp0[i] = u2h2(hw[i]);
#pragma unroll
  for (int i = 0; i < 8; ++i) hp1[i] = u2h2(hw[8 + i]);

  // wc for both points in ONE weight pass (weights from LDS)
  float4 wcv0 = {bwa.x, bwa.y, bwb.x, bwb.y};
  float4 wcv1 = wcv0;
#pragma unroll
  for (int i = 0; i < 8; ++i) {
    uint2 wa = *reinterpret_cast<const uint2*>(&w2s[i * 256 + 2 * l]);
    uint2 wb = *reinterpret_cast<const uint2*>(&w2s[i * 256 + 128 + 2 * l]);
    half2_t wax = u2h2(wa.x), way = u2h2(wa.y);
    half2_t wbx = u2h2(wb.x), wby = u2h2(wb.y);
    wcv0.x = __builtin_amdgcn_fdot2(wax, hp0[i], wcv0.x, false);
    wcv0.y = __builtin_amdgcn_fdot2(way, hp0[i], wcv0.y, false);
    wcv0.z = __builtin_amdgcn_fdot2(wbx, hp0[i], wcv0.z, false);
    wcv0.w = __builtin_amdgcn_fdot2(wby, hp0[i], wcv0.w, false);
    wcv1.x = __builtin_amdgcn_fdot2(wax, hp1[i], wcv1.x, false);
    wcv1.y = __builtin_amdgcn_fdot2(way, hp1[i], wcv1.y, false);
    wcv1.z = __builtin_amdgcn_fdot2(wbx, hp1[i], wcv1.z, false);
    wcv1.w = __builtin_amdgcn_fdot2(wby, hp1[i], wcv1.w, false);
  }

  // transpose stores (layout [mg][kk]: r = mg*16+kk -> slot mg*18+kk), ONE fence
  float* wr0 = wcs[w4][0];
  float* wr1 = wcs[w4][1];
  wr0[q0 * 18 + g0]           = wcv0.x;
  wr0[q0 * 18 + g0 + 1]       = wcv0.y;
  wr0[(q0 + 8) * 18 + g0]     = wcv0.z;
  wr0[(q0 + 8) * 18 + g0 + 1] = wcv0.w;
  wr1[q0 * 18 + g0]           = wcv1.x;
  wr1[q0 * 18 + g0 + 1]       = wcv1.y;
  wr1[(q0 + 8) * 18 + g0]     = wcv1.z;
  wr1[(q0 + 8) * 18 + g0 + 1] = wcv1.w;
  asm volatile("s_waitcnt lgkmcnt(0)" ::: "memory");
  __builtin_amdgcn_sched_barrier(0);

  float2 wrow0[8], wrow1[8];
#pragma unroll
  for (int qq = 0; qq < 8; ++qq) {
    wrow0[qq] = *reinterpret_cast<const float2*>(&wr0[g * 18 + 2 * qq]);
    wrow1[qq] = *reinterpret_cast<const float2*>(&wr1[g * 18 + 2 * qq]);
  }

  // mid[c] = relu(sum_k wc[(c%16)*16+k] * y3[k][c]); lane owns c = l, l+64
  float m0 = 0.f, m1 = 0.f, m2 = 0.f, m3 = 0.f;
#pragma unroll
  for (int k2 = 0; k2 < 16; ++k2) {
    float wc0 = (k2 & 1) ? wrow0[k2 >> 1].y : wrow0[k2 >> 1].x;
    float wc1 = (k2 & 1) ? wrow1[k2 >> 1].y : wrow1[k2 >> 1].x;
    vf2 ya = fp8_f32<false>((unsigned)y3a[k2]);
    vf2 yb = fp8_f32<false>((unsigned)y3b[k2]);
    m0 = fmaf(wc0, ya.x, m0);
    m1 = fmaf(wc0, ya.y, m1);
    m2 = fmaf(wc1, yb.x, m2);
    m3 = fmaf(wc1, yb.y, m3);
  }
  midb[(size_t)pbase * 128 + l]            = f2bf(fmaxf(m0, 0.f));
  midb[(size_t)pbase * 128 + 64 + l]       = f2bf(fmaxf(m1, 0.f));
  midb[(size_t)(pbase + 1) * 128 + l]      = f2bf(fmaxf(m2, 0.f));
  midb[(size_t)(pbase + 1) * 128 + 64 + l] = f2bf(fmaxf(m3, 0.f));
}

// ---------------- kC: out = Wout @ mid + bout + x, bf16 MFMA --------------------------
// XCD-aligned: same batch->XCD-pair mapping as kB (midb read stays in local L2)
__global__ __launch_bounds__(256) void kC(
    const ushort* __restrict__ midb, const ushort* __restrict__ Woutb,
    const float* __restrict__ bout,
    const float* __restrict__ x, float* __restrict__ out)
{
  __shared__ ushort blds[8192];
  __shared__ float ml[128][68];

  const int t = threadIdx.x;
  const int blk = blockIdx.x;                   // 512
  const int xcd = blk & 7;
  const int b  = xcd >> 1;
  const int n0 = (((blk >> 3) << 1) | (xcd & 1)) << 6;
  const int pt0 = b * NPTS + n0;

  const unsigned* mid32 = (const unsigned*)midb;
  unsigned* blds32 = (unsigned*)blds;
#pragma unroll
  for (int i = 0; i < 16; ++i) {
    int e = t + 256 * i;                        // 4096 uints = 64 pts * 64 ch-pairs
    int u = e & 63, p = e >> 6;
    unsigned val = mid32[(size_t)(pt0 + p) * 64 + u];
    int lane = ((u & 15) >> 2) * 16 + (p & 15);
    int fl = (((p >> 4) * 4 + (u >> 4)) * 64 + lane) * 4 + (u & 3);
    blds32[fl] = val;
  }
  __syncthreads();

  const int w = t >> 6, l = t & 63;
  bf16x8 bfr[4];
#pragma unroll
  for (int kt = 0; kt < 4; ++kt)
    bfr[kt] = *reinterpret_cast<const bf16x8*>(&blds[((w * 4 + kt) * 64 + l) * 8]);

  const int rbase = (l >> 4) * 4;
  const int pl = 16 * w + (l & 15);
#pragma unroll
  for (int mt = 0; mt < 8; ++mt) {
    f32x4 acc = {0.f, 0.f, 0.f, 0.f};
#pragma unroll
    for (int kt = 0; kt < 4; ++kt) {
      bf16x8 a = *reinterpret_cast<const bf16x8*>(Woutb + ((size_t)(mt * 4 + kt) * 64 + l) * 8);
      acc = __builtin_amdgcn_mfma_f32_16x16x32_bf16(a, bfr[kt], acc, 0, 0, 0);
    }
#pragma unroll
    for (int r = 0; r < 4; ++r)
      ml[mt * 16 + rbase + r][pl] = acc[r];
  }
  __syncthreads();

  for (int e = t; e < 8192; e += 256) {
    int c = e >> 6, p = e & 63;
    size_t gi = (size_t)(b * 128 + c) * NPTS + n0 + p;
    out[gi] = ml[c][p] + bout[c] + x[gi];
  }
}

extern "C" void kernel_launch(void* const* d_in, const int* in_sizes, int n_in,
                              void* d_out, int out_size, void* d_ws, size_t ws_size,
                              hipStream_t stream)
{
  const float* x    = (const float*)d_in[0];
  const int*   idx  = (const int*)  d_in[1];
  const float* W1   = (const float*)d_in[2];
  const float* b1   = (const float*)d_in[3];
  const float* W2   = (const float*)d_in[4];
  const float* b2   = (const float*)d_in[5];
  const float* W3   = (const float*)d_in[6];
  const float* b3   = (const float*)d_in[7];
  const float* Ww1  = (const float*)d_in[8];
  const float* Ww2  = (const float*)d_in[9];
  const float* bw2  = (const float*)d_in[10];
  const float* Wout = (const float*)d_in[11];
  const float* bout = (const float*)d_in[12];

  float* out     = (float*)d_out;
  float* out_idx = out + (size_t)NB * 128 * NPTS;

  char* wsp = (char*)d_ws;
  unsigned char* Yg = (unsigned char*)wsp; wsp += (size_t)TOTPTS * 128;   // 4.19 MB
  ushort* midb    = (ushort*)wsp;   wsp += (size_t)TOTPTS * 128 * 2;      // 8.39 MB
  unsigned char* V  = (unsigned char*)wsp; wsp += (size_t)TOTPTS * VSTRB; // 9.44 MB
  unsigned* Ww2Pk = (unsigned*)wsp; wsp += 2048 * 4;
  ushort* Wb      = (ushort*)wsp;   wsp += 24576 * 2;
  ushort* Woutb   = (ushort*)wsp;   wsp += 16384 * 2;
  ushort* Wuvb    = (ushort*)wsp;   wsp += 17408 * 2;
  float*  bcat    = (float*)wsp;    wsp += 192 * 4;

  kTW<<<256, 256, 0, stream>>>(W1, W2, W3, b1, b2, b3, Ww1, Ww2, Wout, idx,
                               Ww2Pk, Wb, Woutb, Wuvb, bcat, out_idx);
  kA2<<<512, 256, 0, stream>>>(x, Wb, Wuvb, bcat, Yg, V);
  kB<<<4096, 256, 0, stream>>>(V, Yg, idx, Ww2Pk, bw2, midb);
  kC<<<512,  256, 0, stream>>>(midb, Woutb, bout, x, out);
}